// Round 11
// baseline (410.447 us; speedup 1.0000x reference)
//
#include <hip/hip_runtime.h>

#define N_NODES 100000
#define N_EDGES 640000
#define D 128
#define NLAYERS 4

typedef __attribute__((ext_vector_type(8))) short short8;
typedef __attribute__((ext_vector_type(4))) float f32x4;

// f32 -> bf16 with round-to-nearest-even
__device__ __forceinline__ unsigned short cvbf(float f) {
    unsigned u = __float_as_uint(f);
    return (unsigned short)((u + 0x7fffu + ((u >> 16) & 1u)) >> 16);
}
__device__ __forceinline__ float bf2f(unsigned short b) {
    return __uint_as_float((unsigned)b << 16);
}

// ---------------- CSR build ----------------
__global__ void count_kernel(const int* __restrict__ edge, int* __restrict__ cnt) {
    int e = blockIdx.x * 256 + threadIdx.x;
    if (e < N_EDGES) atomicAdd(&cnt[edge[N_EDGES + e]], 1);
}

__global__ void scan_local(const int* __restrict__ cnt, int* __restrict__ rp,
                           int* __restrict__ bsum) {
    __shared__ int tsum[256];
    int t = threadIdx.x;
    int base = blockIdx.x * 1024 + t * 4;
    int v[4];
#pragma unroll
    for (int j = 0; j < 4; ++j) {
        int i = base + j;
        v[j] = (i < N_NODES) ? cnt[i] : 0;
    }
    int ts = v[0] + v[1] + v[2] + v[3];
    tsum[t] = ts;
    __syncthreads();
    for (int off = 1; off < 256; off <<= 1) {
        int add = (t >= off) ? tsum[t - off] : 0;
        __syncthreads();
        tsum[t] += add;
        __syncthreads();
    }
    int incl = tsum[t];
    int run = incl - ts;
#pragma unroll
    for (int j = 0; j < 4; ++j) {
        int i = base + j;
        if (i < N_NODES) rp[i] = run;
        run += v[j];
    }
    if (t == 255) bsum[blockIdx.x] = incl;
}

// adds prefix of bsum (per-block inclusive sums) computed in-kernel
__global__ void scan_add(int* __restrict__ rp, int* __restrict__ fill,
                         const int* __restrict__ bsum) {
    int add = 0;
    for (int b = 0; b < blockIdx.x; ++b) add += bsum[b];  // uniform scalar loop (98 max)
    int base = blockIdx.x * 1024;
#pragma unroll
    for (int j = 0; j < 4; ++j) {
        int i = base + j * 256 + threadIdx.x;
        if (i < N_NODES) {
            int v = rp[i] + add;
            rp[i] = v;
            fill[i] = v;
        }
    }
    if (blockIdx.x == 0 && threadIdx.x == 0) rp[N_NODES] = N_EDGES;
}

__global__ void fill_kernel(const int* __restrict__ edge, int* __restrict__ fill,
                            int* __restrict__ col) {
    int e = blockIdx.x * 256 + threadIdx.x;
    if (e < N_EDGES) {
        int dst = edge[N_EDGES + e];
        int slot = atomicAdd(&fill[dst], 1);
        col[slot] = edge[e];
    }
}

// ---------------- weight fp32 -> bf16 ----------------
__global__ void wconv(const float* __restrict__ in, unsigned short* __restrict__ out, int n4) {
    int i = blockIdx.x * 256 + threadIdx.x;
    if (i < n4) {
        float4 v = ((const float4*)in)[i];
        ushort4 o;
        o.x = cvbf(v.x);
        o.y = cvbf(v.y);
        o.z = cvbf(v.z);
        o.w = cvbf(v.w);
        ((ushort4*)out)[i] = o;
    }
}

// ---------------- input projection: outb = bf16(x @ W1^T + b1) ----------------
__global__ __launch_bounds__(256, 4) void proj_k(const float* __restrict__ Asrc,
                                                 const short* __restrict__ W1b,
                                                 const float* __restrict__ b1,
                                                 unsigned short* __restrict__ outb, int nrows) {
    __shared__ __align__(16) char smem[32768];
    short8* As = (short8*)smem;  // 16 KB
    float* Of = (float*)smem;    // 32 KB after barrier
    int t = threadIdx.x;
    int rowbase = blockIdx.x * 64;

#pragma unroll
    for (int ch = 0; ch < 4; ++ch) {
        int flat = ch * 256 + t;
        int r = flat >> 4, g = flat & 15;
        int gr = rowbase + r;
        short8 frag = {0, 0, 0, 0, 0, 0, 0, 0};
        if (gr < nrows) {
            const float4* src = (const float4*)Asrc;
            float4 a0 = src[(size_t)gr * 32 + g * 2];
            float4 a1 = src[(size_t)gr * 32 + g * 2 + 1];
            frag[0] = (short)cvbf(a0.x);
            frag[1] = (short)cvbf(a0.y);
            frag[2] = (short)cvbf(a0.z);
            frag[3] = (short)cvbf(a0.w);
            frag[4] = (short)cvbf(a1.x);
            frag[5] = (short)cvbf(a1.y);
            frag[6] = (short)cvbf(a1.z);
            frag[7] = (short)cvbf(a1.w);
        }
        As[r * 16 + (g ^ (r & 7))] = frag;
    }

    int lane = t & 63;
    int w = t >> 6;
    int c0 = w * 32;
    int lrow = lane & 15;
    int lk = lane >> 4;
    int swz = lrow & 7;

    const short8* W1v = (const short8*)W1b;
    short8 bw[2][4];
#pragma unroll
    for (int ct = 0; ct < 2; ++ct)
#pragma unroll
        for (int ks = 0; ks < 4; ++ks)
            bw[ct][ks] = W1v[(size_t)(c0 + ct * 16 + lrow) * 16 + ks * 4 + lk];

    __syncthreads();

    f32x4 zero4 = {0.f, 0.f, 0.f, 0.f};
    f32x4 acc[4][2];
#pragma unroll
    for (int rt = 0; rt < 4; ++rt) {
        acc[rt][0] = zero4;
        acc[rt][1] = zero4;
    }
#pragma unroll
    for (int ks = 0; ks < 4; ++ks) {
        short8 a[4];
#pragma unroll
        for (int rt = 0; rt < 4; ++rt)
            a[rt] = As[(rt * 16 + lrow) * 16 + ((ks * 4 + lk) ^ swz)];
#pragma unroll
        for (int rt = 0; rt < 4; ++rt) {
            acc[rt][0] = __builtin_amdgcn_mfma_f32_16x16x32_bf16(a[rt], bw[0][ks], acc[rt][0], 0, 0, 0);
            acc[rt][1] = __builtin_amdgcn_mfma_f32_16x16x32_bf16(a[rt], bw[1][ks], acc[rt][1], 0, 0, 0);
        }
    }

    float b1v[2] = {b1[c0 + lrow], b1[c0 + 16 + lrow]};
    __syncthreads();
#pragma unroll
    for (int rt = 0; rt < 4; ++rt) {
#pragma unroll
        for (int ct = 0; ct < 2; ++ct) {
            int c = c0 + ct * 16 + lrow;
#pragma unroll
            for (int reg = 0; reg < 4; ++reg) {
                int row = rt * 16 + lk * 4 + reg;
                Of[row * 128 + ((c + ((row >> 2) & 3) * 8) & 127)] = acc[rt][ct][reg] + b1v[ct];
            }
        }
    }
    __syncthreads();

#pragma unroll
    for (int ch = 0; ch < 8; ++ch) {
        int f = ch * 256 + t;
        int row = f >> 5;
        int c4 = f & 31;
        int grow = rowbase + row;
        if (grow >= nrows) continue;
        int pc4 = (c4 + ((row >> 2) & 3) * 2) & 31;
        float4 o = *(const float4*)&Of[row * 128 + pc4 * 4];
        ushort4 ob;
        ob.x = cvbf(o.x);
        ob.y = cvbf(o.y);
        ob.z = cvbf(o.z);
        ob.w = cvbf(o.w);
        ((ushort4*)outb)[(size_t)grow * 32 + c4] = ob;
    }
}

// ================= shared gather macro-body (flat-edge walk into swizzled As) =========
// Each wave owns 16 nodes; their edges form one contiguous col[] range. 16-deep
// load pipeline; flush node means (inv_deg-scaled bf16) at uniform boundary
// crossings using LDS-staged rp bounds.
#define GATHER_PHASE(AsU_)                                                                  \
    {                                                                                       \
        constexpr int U = 16;                                                               \
        int g = lane >> 2;                                                                  \
        int dw = lane & 3;                                                                  \
        int startj = rbl[wv * 17];                                                          \
        int T = rbl[wv * 17 + 16] - startj;                                                 \
        int cur = 0;                                                                        \
        int cur_start = startj;                                                             \
        int cur_end = rbl[wv * 17 + 1];                                                     \
        float ax = 0.f, ay = 0.f;                                                           \
        int u[U];                                                                           \
        _Pragma("unroll") for (int k = 0; k < U; ++k) u[k] = (k < T) ? col[startj + k] : 0; \
        for (int jg = 0; jg < T; jg += U) {                                                 \
            unsigned p[U];                                                                  \
            _Pragma("unroll") for (int k = 0; k < U; ++k)                                   \
                p[k] = (jg + k < T) ? hb_in[(size_t)u[k] * 64 + lane] : 0u;                 \
            _Pragma("unroll") for (int k = 0; k < U; ++k) {                                 \
                int jn = jg + U + k;                                                        \
                if (jn < T) u[k] = col[startj + jn];                                        \
            }                                                                               \
            _Pragma("unroll") for (int k = 0; k < U; ++k) {                                 \
                int ja = startj + jg + k;                                                   \
                if (jg + k >= T) break;                                                     \
                while (ja >= cur_end) {                                                     \
                    int dcur = cur_end - cur_start;                                         \
                    float inv = 1.0f / fmaxf((float)dcur, 1.0f);                            \
                    unsigned pv =                                                           \
                        ((unsigned)cvbf(ay * inv) << 16) | (unsigned)cvbf(ax * inv);        \
                    int r = wv * 16 + cur;                                                  \
                    AsU_[(r * 16 + (g ^ (r & 7))) * 4 + dw] = pv;                           \
                    if (lane == 0) dflag[r] = (dcur > 0) ? 1.0f : 0.0f;                     \
                    ax = 0.f;                                                               \
                    ay = 0.f;                                                               \
                    ++cur;                                                                  \
                    cur_start = cur_end;                                                    \
                    cur_end = rbl[wv * 17 + cur + 1];                                       \
                }                                                                           \
                ax += __uint_as_float(p[k] << 16);                                          \
                ay += __uint_as_float(p[k] & 0xffff0000u);                                  \
            }                                                                               \
        }                                                                                   \
        while (cur < 16) {                                                                  \
            int dcur = cur_end - cur_start;                                                 \
            float inv = 1.0f / fmaxf((float)dcur, 1.0f);                                    \
            unsigned pv = ((unsigned)cvbf(ay * inv) << 16) | (unsigned)cvbf(ax * inv);      \
            int r = wv * 16 + cur;                                                          \
            AsU_[(r * 16 + (g ^ (r & 7))) * 4 + dw] = pv;                                   \
            if (lane == 0) dflag[r] = (dcur > 0) ? 1.0f : 0.0f;                             \
            ax = 0.f;                                                                       \
            ay = 0.f;                                                                       \
            ++cur;                                                                          \
            cur_start = cur_end;                                                            \
            if (cur < 16) cur_end = rbl[wv * 17 + cur + 1];                                 \
        }                                                                                   \
    }

// ---------------- fused GNN mid layer: ONE 16KB LDS tile, phase-aliased ----------------
// Region timeline (barrier-separated): As (gather) -> GEMM1 -> Ts (bf16 T tile) ->
// GEMM2 -> Os (bf16 staged s=acc2+b2) -> epilogue. ~17KB LDS -> up to 8 blocks/CU,
// doubling gather-phase concurrency vs the 33KB variant.
// o = bf16_h + relu(s); carry written to hb_out (ping-pong, != hb_in).
__global__ __launch_bounds__(256, 6) void gnnmid_k(
    const unsigned* __restrict__ hb_in, const int* __restrict__ rp, const int* __restrict__ col,
    const short* __restrict__ W1b, const float* __restrict__ b1,
    const short* __restrict__ W2b, const float* __restrict__ b2,
    unsigned short* __restrict__ hb_out, int nrows) {
    __shared__ __align__(16) char smem[16384];
    __shared__ float dflag[64];
    __shared__ int rbl[4 * 17];
    short8* As = (short8*)smem;
    unsigned* AsU = (unsigned*)smem;
    short* TsS = (short*)smem;
    unsigned short* Os = (unsigned short*)smem;
    int t = threadIdx.x;
    int rowbase = blockIdx.x * 64;
    int lane = t & 63;
    int wv = __builtin_amdgcn_readfirstlane(t >> 6);

    int nbase = rowbase + wv * 16;
    if (lane < 17) rbl[wv * 17 + lane] = rp[min(nbase + lane, N_NODES)];  // own-wave use only

    GATHER_PHASE(AsU)

    int c0 = wv * 32;
    int lrow = lane & 15;
    int lk = lane >> 4;
    int swz = lrow & 7;

    const short8* W1v = (const short8*)W1b;
    short8 bw[2][4];
#pragma unroll
    for (int ct = 0; ct < 2; ++ct)
#pragma unroll
        for (int ks = 0; ks < 4; ++ks)
            bw[ct][ks] = W1v[(size_t)(c0 + ct * 16 + lrow) * 16 + ks * 4 + lk];

    __syncthreads();  // As complete

    f32x4 zero4 = {0.f, 0.f, 0.f, 0.f};
    f32x4 acc[4][2];
#pragma unroll
    for (int rt = 0; rt < 4; ++rt) {
        acc[rt][0] = zero4;
        acc[rt][1] = zero4;
    }
#pragma unroll
    for (int ks = 0; ks < 4; ++ks) {
        short8 a[4];
#pragma unroll
        for (int rt = 0; rt < 4; ++rt)
            a[rt] = As[(rt * 16 + lrow) * 16 + ((ks * 4 + lk) ^ swz)];
#pragma unroll
        for (int rt = 0; rt < 4; ++rt) {
            acc[rt][0] = __builtin_amdgcn_mfma_f32_16x16x32_bf16(a[rt], bw[0][ks], acc[rt][0], 0, 0, 0);
            acc[rt][1] = __builtin_amdgcn_mfma_f32_16x16x32_bf16(a[rt], bw[1][ks], acc[rt][1], 0, 0, 0);
        }
    }

    const short8* W2v = (const short8*)W2b;
    short8 bw2[2][4];
#pragma unroll
    for (int ct = 0; ct < 2; ++ct)
#pragma unroll
        for (int ks = 0; ks < 4; ++ks)
            bw2[ct][ks] = W2v[(size_t)(c0 + ct * 16 + lrow) * 16 + ks * 4 + lk];

    float b1v[2] = {b1[c0 + lrow], b1[c0 + 16 + lrow]};
    __syncthreads();  // all As reads done; region becomes T tile
#pragma unroll
    for (int rt = 0; rt < 4; ++rt) {
#pragma unroll
        for (int ct = 0; ct < 2; ++ct) {
            int c = c0 + ct * 16 + lrow;
            int gh = c >> 3;
#pragma unroll
            for (int reg = 0; reg < 4; ++reg) {
                int rl = rt * 16 + lk * 4 + reg;
                float tv = acc[rt][ct][reg] + b1v[ct] * dflag[rl];
                TsS[rl * 128 + ((gh ^ (rl & 7)) << 3) + (c & 7)] = (short)cvbf(tv);
            }
        }
    }
    __syncthreads();  // T complete

    f32x4 acc2[4][2];
#pragma unroll
    for (int rt = 0; rt < 4; ++rt) {
        acc2[rt][0] = zero4;
        acc2[rt][1] = zero4;
    }
#pragma unroll
    for (int ks = 0; ks < 4; ++ks) {
        short8 a[4];
#pragma unroll
        for (int rt = 0; rt < 4; ++rt)
            a[rt] = As[(rt * 16 + lrow) * 16 + ((ks * 4 + lk) ^ swz)];
#pragma unroll
        for (int rt = 0; rt < 4; ++rt) {
            acc2[rt][0] = __builtin_amdgcn_mfma_f32_16x16x32_bf16(a[rt], bw2[0][ks], acc2[rt][0], 0, 0, 0);
            acc2[rt][1] = __builtin_amdgcn_mfma_f32_16x16x32_bf16(a[rt], bw2[1][ks], acc2[rt][1], 0, 0, 0);
        }
    }

    float b2v[2] = {b2[c0 + lrow], b2[c0 + 16 + lrow]};
    __syncthreads();  // all T reads done; region becomes s tile (bf16)
#pragma unroll
    for (int rt = 0; rt < 4; ++rt) {
#pragma unroll
        for (int ct = 0; ct < 2; ++ct) {
            int c = c0 + ct * 16 + lrow;
            int gh = c >> 3;
#pragma unroll
            for (int reg = 0; reg < 4; ++reg) {
                int rl = rt * 16 + lk * 4 + reg;
                Os[rl * 128 + ((gh ^ (rl & 7)) << 3) + (c & 7)] =
                    cvbf(acc2[rt][ct][reg] + b2v[ct]);
            }
        }
    }
    __syncthreads();

    // epilogue: o = bf16_h + relu(s); coalesced ushort4 reads through the swizzle
    const ushort4* Hb4 = (const ushort4*)hb_in;
#pragma unroll
    for (int ch = 0; ch < 8; ++ch) {
        int f = ch * 256 + t;
        int row = f >> 5;
        int c4 = f & 31;
        int grow = rowbase + row;
        if (grow >= nrows) continue;
        int idx = row * 128 + (((c4 >> 1) ^ (row & 7)) << 3) + (c4 & 1) * 4;
        ushort4 sv = *(const ushort4*)&Os[idx];
        ushort4 hr = Hb4[(size_t)grow * 32 + c4];
        ushort4 ob;
        ob.x = cvbf(bf2f(hr.x) + fmaxf(bf2f(sv.x), 0.f));
        ob.y = cvbf(bf2f(hr.y) + fmaxf(bf2f(sv.y), 0.f));
        ob.z = cvbf(bf2f(hr.z) + fmaxf(bf2f(sv.z), 0.f));
        ob.w = cvbf(bf2f(hr.w) + fmaxf(bf2f(sv.w), 0.f));
        ((ushort4*)hb_out)[(size_t)grow * 32 + c4] = ob;
    }
}

// ---------------- fused GNN last layer (fp32 Of staging, fp32 output) ----------------
__global__ __launch_bounds__(256, 4) void gnnlast_k(
    const unsigned* __restrict__ hb_in, const int* __restrict__ rp, const int* __restrict__ col,
    const short* __restrict__ W1b, const float* __restrict__ b1,
    const short* __restrict__ W2b, const float* __restrict__ b2,
    float* __restrict__ outf, int nrows) {
    __shared__ __align__(16) char smem[32768];
    __shared__ float dflag[64];
    __shared__ int rbl[4 * 17];
    short8* As = (short8*)smem;
    unsigned* AsU = (unsigned*)smem;
    short8* Ts = (short8*)(smem + 16384);
    float* Of = (float*)smem;
    int t = threadIdx.x;
    int rowbase = blockIdx.x * 64;
    int lane = t & 63;
    int wv = __builtin_amdgcn_readfirstlane(t >> 6);

    int nbase = rowbase + wv * 16;
    if (lane < 17) rbl[wv * 17 + lane] = rp[min(nbase + lane, N_NODES)];

    GATHER_PHASE(AsU)

    int c0 = wv * 32;
    int lrow = lane & 15;
    int lk = lane >> 4;
    int swz = lrow & 7;

    const short8* W1v = (const short8*)W1b;
    short8 bw[2][4];
#pragma unroll
    for (int ct = 0; ct < 2; ++ct)
#pragma unroll
        for (int ks = 0; ks < 4; ++ks)
            bw[ct][ks] = W1v[(size_t)(c0 + ct * 16 + lrow) * 16 + ks * 4 + lk];

    __syncthreads();

    f32x4 zero4 = {0.f, 0.f, 0.f, 0.f};
    f32x4 acc[4][2];
#pragma unroll
    for (int rt = 0; rt < 4; ++rt) {
        acc[rt][0] = zero4;
        acc[rt][1] = zero4;
    }
#pragma unroll
    for (int ks = 0; ks < 4; ++ks) {
        short8 a[4];
#pragma unroll
        for (int rt = 0; rt < 4; ++rt)
            a[rt] = As[(rt * 16 + lrow) * 16 + ((ks * 4 + lk) ^ swz)];
#pragma unroll
        for (int rt = 0; rt < 4; ++rt) {
            acc[rt][0] = __builtin_amdgcn_mfma_f32_16x16x32_bf16(a[rt], bw[0][ks], acc[rt][0], 0, 0, 0);
            acc[rt][1] = __builtin_amdgcn_mfma_f32_16x16x32_bf16(a[rt], bw[1][ks], acc[rt][1], 0, 0, 0);
        }
    }

    const short8* W2v = (const short8*)W2b;
    short8 bw2[2][4];
#pragma unroll
    for (int ct = 0; ct < 2; ++ct)
#pragma unroll
        for (int ks = 0; ks < 4; ++ks)
            bw2[ct][ks] = W2v[(size_t)(c0 + ct * 16 + lrow) * 16 + ks * 4 + lk];

    float b1v[2] = {b1[c0 + lrow], b1[c0 + 16 + lrow]};
    short* TsS = (short*)Ts;
#pragma unroll
    for (int rt = 0; rt < 4; ++rt) {
#pragma unroll
        for (int ct = 0; ct < 2; ++ct) {
            int c = c0 + ct * 16 + lrow;
            int gh = c >> 3;
#pragma unroll
            for (int reg = 0; reg < 4; ++reg) {
                int rl = rt * 16 + lk * 4 + reg;
                float tv = acc[rt][ct][reg] + b1v[ct] * dflag[rl];
                TsS[rl * 128 + ((gh ^ (rl & 7)) << 3) + (c & 7)] = (short)cvbf(tv);
            }
        }
    }
    __syncthreads();

    f32x4 acc2[4][2];
#pragma unroll
    for (int rt = 0; rt < 4; ++rt) {
        acc2[rt][0] = zero4;
        acc2[rt][1] = zero4;
    }
#pragma unroll
    for (int ks = 0; ks < 4; ++ks) {
        short8 a[4];
#pragma unroll
        for (int rt = 0; rt < 4; ++rt)
            a[rt] = Ts[(rt * 16 + lrow) * 16 + ((ks * 4 + lk) ^ swz)];
#pragma unroll
        for (int rt = 0; rt < 4; ++rt) {
            acc2[rt][0] = __builtin_amdgcn_mfma_f32_16x16x32_bf16(a[rt], bw2[0][ks], acc2[rt][0], 0, 0, 0);
            acc2[rt][1] = __builtin_amdgcn_mfma_f32_16x16x32_bf16(a[rt], bw2[1][ks], acc2[rt][1], 0, 0, 0);
        }
    }

    float b2v[2] = {b2[c0 + lrow], b2[c0 + 16 + lrow]};
    __syncthreads();  // As/Ts dead; Of takes over
#pragma unroll
    for (int rt = 0; rt < 4; ++rt) {
#pragma unroll
        for (int ct = 0; ct < 2; ++ct) {
            int c = c0 + ct * 16 + lrow;
#pragma unroll
            for (int reg = 0; reg < 4; ++reg) {
                int row = rt * 16 + lk * 4 + reg;
                Of[row * 128 + ((c + ((row >> 2) & 3) * 8) & 127)] = acc2[rt][ct][reg] + b2v[ct];
            }
        }
    }
    __syncthreads();

    const ushort4* Hb4 = (const ushort4*)hb_in;
#pragma unroll
    for (int ch = 0; ch < 8; ++ch) {
        int f = ch * 256 + t;
        int row = f >> 5;
        int c4 = f & 31;
        int grow = rowbase + row;
        if (grow >= nrows) continue;
        int pc4 = (c4 + ((row >> 2) & 3) * 2) & 31;
        float4 v = *(const float4*)&Of[row * 128 + pc4 * 4];
        ushort4 hr = Hb4[(size_t)grow * 32 + c4];
        float4 o;
        o.x = bf2f(hr.x) + fmaxf(v.x, 0.f);
        o.y = bf2f(hr.y) + fmaxf(v.y, 0.f);
        o.z = bf2f(hr.z) + fmaxf(v.z, 0.f);
        o.w = bf2f(hr.w) + fmaxf(v.w, 0.f);
        ((float4*)outf)[(size_t)grow * 32 + c4] = o;
    }
}

extern "C" void kernel_launch(void* const* d_in, const int* in_sizes, int n_in,
                              void* d_out, int out_size, void* d_ws, size_t ws_size,
                              hipStream_t stream) {
    const float* x = (const float*)d_in[0];
    const float* Wi = (const float*)d_in[1];
    const float* bi = (const float*)d_in[2];
    const float* Wm = (const float*)d_in[3];
    const float* bm = (const float*)d_in[4];
    const float* Wu = (const float*)d_in[5];
    const float* bu = (const float*)d_in[6];
    const int* edge = (const int*)d_in[7];
    float* h = (float*)d_out;

    char* ws = (char*)d_ws;
    size_t off = 0;
    auto alloc = [&](size_t bytes) {
        void* p = ws + off;
        off += (bytes + 255) & ~(size_t)255;
        return p;
    };
    unsigned short* hbuf[2];
    hbuf[0] = (unsigned short*)alloc((size_t)N_NODES * D * 2);
    hbuf[1] = (unsigned short*)alloc((size_t)N_NODES * D * 2);
    unsigned short* Wi_bf = (unsigned short*)alloc((size_t)D * D * 2);
    unsigned short* Wm_bf = (unsigned short*)alloc((size_t)NLAYERS * D * D * 2);
    unsigned short* Wu_bf = (unsigned short*)alloc((size_t)NLAYERS * D * D * 2);
    int* cnt = (int*)alloc((size_t)N_NODES * sizeof(int));
    int* rp = (int*)alloc((size_t)(N_NODES + 1) * sizeof(int));
    int* fill = (int*)alloc((size_t)N_NODES * sizeof(int));
    int* bsum = (int*)alloc(1024 * sizeof(int));
    int* col = (int*)alloc((size_t)N_EDGES * sizeof(int));

    const int scan_blocks = (N_NODES + 1023) / 1024;  // 98
    const int edge_blocks = (N_EDGES + 255) / 256;    // 2500
    const int gemm_blocks = (N_NODES + 63) / 64;      // 1563

    // CSR build
    hipMemsetAsync(cnt, 0, (size_t)N_NODES * sizeof(int), stream);
    count_kernel<<<edge_blocks, 256, 0, stream>>>(edge, cnt);
    scan_local<<<scan_blocks, 256, 0, stream>>>(cnt, rp, bsum);
    scan_add<<<scan_blocks, 256, 0, stream>>>(rp, fill, bsum);
    fill_kernel<<<edge_blocks, 256, 0, stream>>>(edge, fill, col);

    // weights -> bf16
    wconv<<<(D * D / 4 + 255) / 256, 256, 0, stream>>>(Wi, Wi_bf, D * D / 4);
    wconv<<<(NLAYERS * D * D / 4 + 255) / 256, 256, 0, stream>>>(Wm, Wm_bf, NLAYERS * D * D / 4);
    wconv<<<(NLAYERS * D * D / 4 + 255) / 256, 256, 0, stream>>>(Wu, Wu_bf, NLAYERS * D * D / 4);

    // input projection: hbuf[0] = bf16(x @ Wi^T + bi)
    proj_k<<<gemm_blocks, 256, 0, stream>>>(x, (const short*)Wi_bf, bi, hbuf[0], N_NODES);

    for (int l = 0; l < NLAYERS - 1; ++l) {
        gnnmid_k<<<gemm_blocks, 256, 0, stream>>>(
            (const unsigned*)hbuf[l & 1], rp, col,
            (const short*)(Wm_bf + (size_t)l * D * D), bm + (size_t)l * D,
            (const short*)(Wu_bf + (size_t)l * D * D), bu + (size_t)l * D, hbuf[(l + 1) & 1],
            N_NODES);
    }
    {
        int l = NLAYERS - 1;
        gnnlast_k<<<gemm_blocks, 256, 0, stream>>>(
            (const unsigned*)hbuf[l & 1], rp, col,
            (const short*)(Wm_bf + (size_t)l * D * D), bm + (size_t)l * D,
            (const short*)(Wu_bf + (size_t)l * D * D), bu + (size_t)l * D, h, N_NODES);
    }
}

// Round 12
// 337.037 us; speedup vs baseline: 1.2178x; 1.2178x over previous
//
#include <hip/hip_runtime.h>

#define N_NODES 100000
#define N_EDGES 640000
#define D 128
#define NLAYERS 4

typedef __attribute__((ext_vector_type(8))) short short8;
typedef __attribute__((ext_vector_type(4))) float f32x4;

// f32 -> bf16 with round-to-nearest-even
__device__ __forceinline__ unsigned short cvbf(float f) {
    unsigned u = __float_as_uint(f);
    return (unsigned short)((u + 0x7fffu + ((u >> 16) & 1u)) >> 16);
}
__device__ __forceinline__ float bf2f(unsigned short b) {
    return __uint_as_float((unsigned)b << 16);
}

// ---------------- CSR build ----------------
__global__ void count_kernel(const int* __restrict__ edge, int* __restrict__ cnt) {
    int e = blockIdx.x * 256 + threadIdx.x;
    if (e < N_EDGES) atomicAdd(&cnt[edge[N_EDGES + e]], 1);
}

__global__ void scan_local(const int* __restrict__ cnt, int* __restrict__ rp,
                           int* __restrict__ bsum) {
    __shared__ int tsum[256];
    int t = threadIdx.x;
    int base = blockIdx.x * 1024 + t * 4;
    int v[4];
#pragma unroll
    for (int j = 0; j < 4; ++j) {
        int i = base + j;
        v[j] = (i < N_NODES) ? cnt[i] : 0;
    }
    int ts = v[0] + v[1] + v[2] + v[3];
    tsum[t] = ts;
    __syncthreads();
    for (int off = 1; off < 256; off <<= 1) {
        int add = (t >= off) ? tsum[t - off] : 0;
        __syncthreads();
        tsum[t] += add;
        __syncthreads();
    }
    int incl = tsum[t];
    int run = incl - ts;
#pragma unroll
    for (int j = 0; j < 4; ++j) {
        int i = base + j;
        if (i < N_NODES) rp[i] = run;
        run += v[j];
    }
    if (t == 255) bsum[blockIdx.x] = incl;
}

// adds prefix of bsum (per-block inclusive sums) computed in-kernel
__global__ void scan_add(int* __restrict__ rp, int* __restrict__ fill,
                         const int* __restrict__ bsum) {
    int add = 0;
    for (int b = 0; b < blockIdx.x; ++b) add += bsum[b];  // uniform scalar loop (98 max)
    int base = blockIdx.x * 1024;
#pragma unroll
    for (int j = 0; j < 4; ++j) {
        int i = base + j * 256 + threadIdx.x;
        if (i < N_NODES) {
            int v = rp[i] + add;
            rp[i] = v;
            fill[i] = v;
        }
    }
    if (blockIdx.x == 0 && threadIdx.x == 0) rp[N_NODES] = N_EDGES;
}

__global__ void fill_kernel(const int* __restrict__ edge, int* __restrict__ fill,
                            int* __restrict__ col) {
    int e = blockIdx.x * 256 + threadIdx.x;
    if (e < N_EDGES) {
        int dst = edge[N_EDGES + e];
        int slot = atomicAdd(&fill[dst], 1);
        col[slot] = edge[e];
    }
}

// ---------------- weight fp32 -> bf16 ----------------
__global__ void wconv(const float* __restrict__ in, unsigned short* __restrict__ out, int n4) {
    int i = blockIdx.x * 256 + threadIdx.x;
    if (i < n4) {
        float4 v = ((const float4*)in)[i];
        ushort4 o;
        o.x = cvbf(v.x);
        o.y = cvbf(v.y);
        o.z = cvbf(v.z);
        o.w = cvbf(v.w);
        ((ushort4*)out)[i] = o;
    }
}

// ---------------- input projection: outf = x @ W1^T + b1 (+ bf16 mirror) ----------------
__global__ __launch_bounds__(256, 4) void proj_k(const float* __restrict__ Asrc,
                                                 const short* __restrict__ W1b,
                                                 const float* __restrict__ b1,
                                                 float* __restrict__ outf,
                                                 unsigned short* __restrict__ outb, int nrows) {
    __shared__ __align__(16) char smem[32768];
    short8* As = (short8*)smem;  // 16 KB
    float* Of = (float*)smem;    // 32 KB after barrier
    int t = threadIdx.x;
    int rowbase = blockIdx.x * 64;

#pragma unroll
    for (int ch = 0; ch < 4; ++ch) {
        int flat = ch * 256 + t;
        int r = flat >> 4, g = flat & 15;
        int gr = rowbase + r;
        short8 frag = {0, 0, 0, 0, 0, 0, 0, 0};
        if (gr < nrows) {
            const float4* src = (const float4*)Asrc;
            float4 a0 = src[(size_t)gr * 32 + g * 2];
            float4 a1 = src[(size_t)gr * 32 + g * 2 + 1];
            frag[0] = (short)cvbf(a0.x);
            frag[1] = (short)cvbf(a0.y);
            frag[2] = (short)cvbf(a0.z);
            frag[3] = (short)cvbf(a0.w);
            frag[4] = (short)cvbf(a1.x);
            frag[5] = (short)cvbf(a1.y);
            frag[6] = (short)cvbf(a1.z);
            frag[7] = (short)cvbf(a1.w);
        }
        As[r * 16 + (g ^ (r & 7))] = frag;
    }

    int lane = t & 63;
    int w = t >> 6;
    int c0 = w * 32;
    int lrow = lane & 15;
    int lk = lane >> 4;
    int swz = lrow & 7;

    const short8* W1v = (const short8*)W1b;
    short8 bw[2][4];
#pragma unroll
    for (int ct = 0; ct < 2; ++ct)
#pragma unroll
        for (int ks = 0; ks < 4; ++ks)
            bw[ct][ks] = W1v[(size_t)(c0 + ct * 16 + lrow) * 16 + ks * 4 + lk];

    __syncthreads();

    f32x4 zero4 = {0.f, 0.f, 0.f, 0.f};
    f32x4 acc[4][2];
#pragma unroll
    for (int rt = 0; rt < 4; ++rt) {
        acc[rt][0] = zero4;
        acc[rt][1] = zero4;
    }
#pragma unroll
    for (int ks = 0; ks < 4; ++ks) {
        short8 a[4];
#pragma unroll
        for (int rt = 0; rt < 4; ++rt)
            a[rt] = As[(rt * 16 + lrow) * 16 + ((ks * 4 + lk) ^ swz)];
#pragma unroll
        for (int rt = 0; rt < 4; ++rt) {
            acc[rt][0] = __builtin_amdgcn_mfma_f32_16x16x32_bf16(a[rt], bw[0][ks], acc[rt][0], 0, 0, 0);
            acc[rt][1] = __builtin_amdgcn_mfma_f32_16x16x32_bf16(a[rt], bw[1][ks], acc[rt][1], 0, 0, 0);
        }
    }

    float b1v[2] = {b1[c0 + lrow], b1[c0 + 16 + lrow]};
    __syncthreads();
#pragma unroll
    for (int rt = 0; rt < 4; ++rt) {
#pragma unroll
        for (int ct = 0; ct < 2; ++ct) {
            int c = c0 + ct * 16 + lrow;
#pragma unroll
            for (int reg = 0; reg < 4; ++reg) {
                int row = rt * 16 + lk * 4 + reg;
                Of[row * 128 + ((c + ((row >> 2) & 3) * 8) & 127)] = acc[rt][ct][reg] + b1v[ct];
            }
        }
    }
    __syncthreads();

#pragma unroll
    for (int ch = 0; ch < 8; ++ch) {
        int f = ch * 256 + t;
        int row = f >> 5;
        int c4 = f & 31;
        int grow = rowbase + row;
        if (grow >= nrows) continue;
        int pc4 = (c4 + ((row >> 2) & 3) * 2) & 31;
        float4 o = *(const float4*)&Of[row * 128 + pc4 * 4];
        ((float4*)outf)[(size_t)grow * 32 + c4] = o;
        ushort4 ob;
        ob.x = cvbf(o.x);
        ob.y = cvbf(o.y);
        ob.z = cvbf(o.z);
        ob.w = cvbf(o.w);
        ((ushort4*)outb)[(size_t)grow * 32 + c4] = ob;
    }
}

// ---------------- fused GNN layer: 16 KB phase-aliased LDS, 8 blocks/CU ----------------
// Region timeline (barrier-separated): As (gathered bf16 agg, swizzled) -> GEMM1 ->
// Ts (bf16 T) -> GEMM2 -> Os (bf16 s=acc2+b2) -> epilogue o = Hin + relu(s).
// Gather: R7-proven 16 interleaved node-chains/wave, all static indexing, upfront
// CSR bounds via readfirstlane (SGPRs). fp32 h carry in Hin/outf; bf16 mirror optional.
// RACE NOTE: hb_out != hb_in (ping-pong); Hin/outf touch own rows only.
__global__ __launch_bounds__(256, 4) void gnnlayer_k(
    const unsigned* __restrict__ hb_in, const int* __restrict__ rp, const int* __restrict__ col,
    const int* __restrict__ cnt, const short* __restrict__ W1b, const float* __restrict__ b1,
    const short* __restrict__ W2b, const float* __restrict__ b2, const float* __restrict__ Hin,
    float* __restrict__ outf, unsigned short* __restrict__ hb_out, int nrows) {
    __shared__ __align__(16) char smem[16384];
    __shared__ float dflag[64];
    short8* As = (short8*)smem;
    short* TsS = (short*)smem;
    unsigned short* Os = (unsigned short*)smem;
    int t = threadIdx.x;
    int rowbase = blockIdx.x * 64;
    int lane = t & 63;
    int wv = __builtin_amdgcn_readfirstlane(t >> 6);  // 0..3

    // ---- gather-aggregate phase: this wave owns nodes nbase..nbase+16 ----
    {
        int nbase = rowbase + wv * 16;
        int rb[17];
#pragma unroll
        for (int i = 0; i <= 16; ++i)
            rb[i] = __builtin_amdgcn_readfirstlane(rp[min(nbase + i, N_NODES)]);
        int d[16];
        int maxd = 0;
#pragma unroll
        for (int i = 0; i < 16; ++i) {
            d[i] = rb[i + 1] - rb[i];
            maxd = max(maxd, d[i]);
        }

        float ax[16], ay[16];
        int u[16];
#pragma unroll
        for (int i = 0; i < 16; ++i) {
            ax[i] = 0.f;
            ay[i] = 0.f;
            u[i] = 0;
        }
#pragma unroll
        for (int i = 0; i < 16; ++i)
            if (0 < d[i]) u[i] = col[rb[i]];  // wave-uniform -> s_load

        for (int j = 0; j < maxd; ++j) {
            unsigned p[16];
            // issue all active gathers first (independent -> in flight together)
#pragma unroll
            for (int i = 0; i < 16; ++i)
                p[i] = (j < d[i]) ? hb_in[(size_t)u[i] * 64 + lane] : 0u;
            int jn = j + 1;
#pragma unroll
            for (int i = 0; i < 16; ++i)
                if (jn < d[i]) u[i] = col[rb[i] + jn];
#pragma unroll
            for (int i = 0; i < 16; ++i) {
                ax[i] += __uint_as_float(p[i] << 16);
                ay[i] += __uint_as_float(p[i] & 0xffff0000u);
            }
        }

        // write aggregated rows (bf16, inv_deg-scaled) into swizzled As tile.
        unsigned* AsU = (unsigned*)As;
        int g = lane >> 2;
        int dw = lane & 3;
#pragma unroll
        for (int i = 0; i < 16; ++i) {
            float inv = 1.0f / fmaxf((float)d[i], 1.0f);
            unsigned pv = ((unsigned)cvbf(ay[i] * inv) << 16) | (unsigned)cvbf(ax[i] * inv);
            int r = wv * 16 + i;
            AsU[(r * 16 + (g ^ (r & 7))) * 4 + dw] = pv;
        }
    }
    if (t < 64) {
        int gr = rowbase + t;
        dflag[t] = (gr < nrows && cnt[gr] > 0) ? 1.0f : 0.0f;
    }

    int c0 = wv * 32;
    int lrow = lane & 15;
    int lk = lane >> 4;
    int swz = lrow & 7;

    const short8* W1v = (const short8*)W1b;
    short8 bw[2][4];
#pragma unroll
    for (int ct = 0; ct < 2; ++ct)
#pragma unroll
        for (int ks = 0; ks < 4; ++ks)
            bw[ct][ks] = W1v[(size_t)(c0 + ct * 16 + lrow) * 16 + ks * 4 + lk];

    __syncthreads();  // As + dflag complete

    f32x4 zero4 = {0.f, 0.f, 0.f, 0.f};
    f32x4 acc[4][2];
#pragma unroll
    for (int rt = 0; rt < 4; ++rt) {
        acc[rt][0] = zero4;
        acc[rt][1] = zero4;
    }
#pragma unroll
    for (int ks = 0; ks < 4; ++ks) {
        short8 a[4];
#pragma unroll
        for (int rt = 0; rt < 4; ++rt)
            a[rt] = As[(rt * 16 + lrow) * 16 + ((ks * 4 + lk) ^ swz)];
#pragma unroll
        for (int rt = 0; rt < 4; ++rt) {
            acc[rt][0] = __builtin_amdgcn_mfma_f32_16x16x32_bf16(a[rt], bw[0][ks], acc[rt][0], 0, 0, 0);
            acc[rt][1] = __builtin_amdgcn_mfma_f32_16x16x32_bf16(a[rt], bw[1][ks], acc[rt][1], 0, 0, 0);
        }
    }

    const short8* W2v = (const short8*)W2b;
    short8 bw2[2][4];
#pragma unroll
    for (int ct = 0; ct < 2; ++ct)
#pragma unroll
        for (int ks = 0; ks < 4; ++ks)
            bw2[ct][ks] = W2v[(size_t)(c0 + ct * 16 + lrow) * 16 + ks * 4 + lk];

    float b1v[2] = {b1[c0 + lrow], b1[c0 + 16 + lrow]};
    __syncthreads();  // all As reads done; region becomes T tile
#pragma unroll
    for (int rt = 0; rt < 4; ++rt) {
#pragma unroll
        for (int ct = 0; ct < 2; ++ct) {
            int c = c0 + ct * 16 + lrow;
            int gh = c >> 3;
#pragma unroll
            for (int reg = 0; reg < 4; ++reg) {
                int rl = rt * 16 + lk * 4 + reg;  // C/D: row=(lane>>4)*4+reg
                float tv = acc[rt][ct][reg] + b1v[ct] * dflag[rl];
                TsS[rl * 128 + ((gh ^ (rl & 7)) << 3) + (c & 7)] = (short)cvbf(tv);
            }
        }
    }
    __syncthreads();  // T complete

    f32x4 acc2[4][2];
#pragma unroll
    for (int rt = 0; rt < 4; ++rt) {
        acc2[rt][0] = zero4;
        acc2[rt][1] = zero4;
    }
#pragma unroll
    for (int ks = 0; ks < 4; ++ks) {
        short8 a[4];
#pragma unroll
        for (int rt = 0; rt < 4; ++rt)
            a[rt] = As[(rt * 16 + lrow) * 16 + ((ks * 4 + lk) ^ swz)];  // region holds T now
#pragma unroll
        for (int rt = 0; rt < 4; ++rt) {
            acc2[rt][0] = __builtin_amdgcn_mfma_f32_16x16x32_bf16(a[rt], bw2[0][ks], acc2[rt][0], 0, 0, 0);
            acc2[rt][1] = __builtin_amdgcn_mfma_f32_16x16x32_bf16(a[rt], bw2[1][ks], acc2[rt][1], 0, 0, 0);
        }
    }

    float b2v[2] = {b2[c0 + lrow], b2[c0 + 16 + lrow]};
    __syncthreads();  // all T reads done; region becomes s tile (bf16)
#pragma unroll
    for (int rt = 0; rt < 4; ++rt) {
#pragma unroll
        for (int ct = 0; ct < 2; ++ct) {
            int c = c0 + ct * 16 + lrow;
            int gh = c >> 3;
#pragma unroll
            for (int reg = 0; reg < 4; ++reg) {
                int rl = rt * 16 + lk * 4 + reg;
                Os[rl * 128 + ((gh ^ (rl & 7)) << 3) + (c & 7)] =
                    cvbf(acc2[rt][ct][reg] + b2v[ct]);
            }
        }
    }
    __syncthreads();

    // epilogue: o = Hin + relu(s); fp32 out (own rows) + optional bf16 mirror
    const float4* Hin4 = (const float4*)Hin;
#pragma unroll
    for (int ch = 0; ch < 8; ++ch) {
        int f = ch * 256 + t;
        int row = f >> 5;
        int c4 = f & 31;
        int grow = rowbase + row;
        if (grow >= nrows) continue;
        int idx = row * 128 + (((c4 >> 1) ^ (row & 7)) << 3) + (c4 & 1) * 4;
        ushort4 sv = *(const ushort4*)&Os[idx];
        float4 hv = Hin4[(size_t)grow * 32 + c4];
        float4 o;
        o.x = hv.x + fmaxf(bf2f(sv.x), 0.f);
        o.y = hv.y + fmaxf(bf2f(sv.y), 0.f);
        o.z = hv.z + fmaxf(bf2f(sv.z), 0.f);
        o.w = hv.w + fmaxf(bf2f(sv.w), 0.f);
        ((float4*)outf)[(size_t)grow * 32 + c4] = o;
        if (hb_out) {
            ushort4 ob;
            ob.x = cvbf(o.x);
            ob.y = cvbf(o.y);
            ob.z = cvbf(o.z);
            ob.w = cvbf(o.w);
            ((ushort4*)hb_out)[(size_t)grow * 32 + c4] = ob;
        }
    }
}

extern "C" void kernel_launch(void* const* d_in, const int* in_sizes, int n_in,
                              void* d_out, int out_size, void* d_ws, size_t ws_size,
                              hipStream_t stream) {
    const float* x = (const float*)d_in[0];
    const float* Wi = (const float*)d_in[1];
    const float* bi = (const float*)d_in[2];
    const float* Wm = (const float*)d_in[3];
    const float* bm = (const float*)d_in[4];
    const float* Wu = (const float*)d_in[5];
    const float* bu = (const float*)d_in[6];
    const int* edge = (const int*)d_in[7];
    float* h = (float*)d_out;

    char* ws = (char*)d_ws;
    size_t off = 0;
    auto alloc = [&](size_t bytes) {
        void* p = ws + off;
        off += (bytes + 255) & ~(size_t)255;
        return p;
    };
    // ping-pong bf16 mirrors of h (avoids cross-block RAW race in fused layers)
    unsigned short* hbuf[2];
    hbuf[0] = (unsigned short*)alloc((size_t)N_NODES * D * 2);
    hbuf[1] = (unsigned short*)alloc((size_t)N_NODES * D * 2);
    unsigned short* Wi_bf = (unsigned short*)alloc((size_t)D * D * 2);
    unsigned short* Wm_bf = (unsigned short*)alloc((size_t)NLAYERS * D * D * 2);
    unsigned short* Wu_bf = (unsigned short*)alloc((size_t)NLAYERS * D * D * 2);
    int* cnt = (int*)alloc((size_t)N_NODES * sizeof(int));
    int* rp = (int*)alloc((size_t)(N_NODES + 1) * sizeof(int));
    int* fill = (int*)alloc((size_t)N_NODES * sizeof(int));
    int* bsum = (int*)alloc(1024 * sizeof(int));
    int* col = (int*)alloc((size_t)N_EDGES * sizeof(int));

    const int scan_blocks = (N_NODES + 1023) / 1024;  // 98
    const int edge_blocks = (N_EDGES + 255) / 256;    // 2500
    const int gemm_blocks = (N_NODES + 63) / 64;      // 1563

    // CSR build
    hipMemsetAsync(cnt, 0, (size_t)N_NODES * sizeof(int), stream);
    count_kernel<<<edge_blocks, 256, 0, stream>>>(edge, cnt);
    scan_local<<<scan_blocks, 256, 0, stream>>>(cnt, rp, bsum);
    scan_add<<<scan_blocks, 256, 0, stream>>>(rp, fill, bsum);
    fill_kernel<<<edge_blocks, 256, 0, stream>>>(edge, fill, col);

    // weights -> bf16
    wconv<<<(D * D / 4 + 255) / 256, 256, 0, stream>>>(Wi, Wi_bf, D * D / 4);
    wconv<<<(NLAYERS * D * D / 4 + 255) / 256, 256, 0, stream>>>(Wm, Wm_bf, NLAYERS * D * D / 4);
    wconv<<<(NLAYERS * D * D / 4 + 255) / 256, 256, 0, stream>>>(Wu, Wu_bf, NLAYERS * D * D / 4);

    // input projection: h = x @ Wi^T + bi  (fp32 out + bf16 mirror into hbuf[0])
    proj_k<<<gemm_blocks, 256, 0, stream>>>(x, (const short*)Wi_bf, bi, h, hbuf[0], N_NODES);

    for (int l = 0; l < NLAYERS; ++l) {
        // read mirror hbuf[l&1], write mirror hbuf[(l+1)&1] (none on last layer)
        unsigned short* mirror = (l == NLAYERS - 1) ? nullptr : hbuf[(l + 1) & 1];
        gnnlayer_k<<<gemm_blocks, 256, 0, stream>>>(
            (const unsigned*)hbuf[l & 1], rp, col, cnt,
            (const short*)(Wm_bf + (size_t)l * D * D), bm + (size_t)l * D,
            (const short*)(Wu_bf + (size_t)l * D * D), bu + (size_t)l * D, h, h, mirror,
            N_NODES);
    }
}

// Round 13
// 298.636 us; speedup vs baseline: 1.3744x; 1.1286x over previous
//
#include <hip/hip_runtime.h>

#define N_NODES 100000
#define N_EDGES 640000
#define D 128
#define NLAYERS 4

typedef __attribute__((ext_vector_type(8))) short short8;
typedef __attribute__((ext_vector_type(4))) float f32x4;

// f32 -> bf16 with round-to-nearest-even
__device__ __forceinline__ unsigned short cvbf(float f) {
    unsigned u = __float_as_uint(f);
    return (unsigned short)((u + 0x7fffu + ((u >> 16) & 1u)) >> 16);
}
__device__ __forceinline__ float bflo(unsigned u) {  // low bf16 of packed u32
    return __uint_as_float(u << 16);
}
__device__ __forceinline__ float bfhi(unsigned u) {  // high bf16 of packed u32
    return __uint_as_float(u & 0xffff0000u);
}

// ---------------- CSR build ----------------
__global__ void count_kernel(const int* __restrict__ edge, int* __restrict__ cnt) {
    int e = blockIdx.x * 256 + threadIdx.x;
    if (e < N_EDGES) atomicAdd(&cnt[edge[N_EDGES + e]], 1);
}

__global__ void scan_local(const int* __restrict__ cnt, int* __restrict__ rp,
                           int* __restrict__ bsum) {
    __shared__ int tsum[256];
    int t = threadIdx.x;
    int base = blockIdx.x * 1024 + t * 4;
    int v[4];
#pragma unroll
    for (int j = 0; j < 4; ++j) {
        int i = base + j;
        v[j] = (i < N_NODES) ? cnt[i] : 0;
    }
    int ts = v[0] + v[1] + v[2] + v[3];
    tsum[t] = ts;
    __syncthreads();
    for (int off = 1; off < 256; off <<= 1) {
        int add = (t >= off) ? tsum[t - off] : 0;
        __syncthreads();
        tsum[t] += add;
        __syncthreads();
    }
    int incl = tsum[t];
    int run = incl - ts;
#pragma unroll
    for (int j = 0; j < 4; ++j) {
        int i = base + j;
        if (i < N_NODES) rp[i] = run;
        run += v[j];
    }
    if (t == 255) bsum[blockIdx.x] = incl;
}

// adds prefix of bsum (per-block inclusive sums) computed in-kernel
__global__ void scan_add(int* __restrict__ rp, int* __restrict__ fill,
                         const int* __restrict__ bsum) {
    int add = 0;
    for (int b = 0; b < blockIdx.x; ++b) add += bsum[b];  // uniform scalar loop (98 max)
    int base = blockIdx.x * 1024;
#pragma unroll
    for (int j = 0; j < 4; ++j) {
        int i = base + j * 256 + threadIdx.x;
        if (i < N_NODES) {
            int v = rp[i] + add;
            rp[i] = v;
            fill[i] = v;
        }
    }
    if (blockIdx.x == 0 && threadIdx.x == 0) rp[N_NODES] = N_EDGES;
}

__global__ void fill_kernel(const int* __restrict__ edge, int* __restrict__ fill,
                            int* __restrict__ col) {
    int e = blockIdx.x * 256 + threadIdx.x;
    if (e < N_EDGES) {
        int dst = edge[N_EDGES + e];
        int slot = atomicAdd(&fill[dst], 1);
        col[slot] = edge[e];
    }
}

// ---------------- weight fp32 -> bf16 ----------------
__global__ void wconv(const float* __restrict__ in, unsigned short* __restrict__ out, int n4) {
    int i = blockIdx.x * 256 + threadIdx.x;
    if (i < n4) {
        float4 v = ((const float4*)in)[i];
        ushort4 o;
        o.x = cvbf(v.x);
        o.y = cvbf(v.y);
        o.z = cvbf(v.z);
        o.w = cvbf(v.w);
        ((ushort4*)out)[i] = o;
    }
}

// ---------------- input projection: outb = bf16(x @ W1^T + b1) ----------------
__global__ __launch_bounds__(256, 4) void proj_k(const float* __restrict__ Asrc,
                                                 const short* __restrict__ W1b,
                                                 const float* __restrict__ b1,
                                                 unsigned* __restrict__ outb, int nrows) {
    __shared__ __align__(16) char smem[32768];
    short8* As = (short8*)smem;  // 16 KB
    float* Of = (float*)smem;    // 32 KB after barrier
    int t = threadIdx.x;
    int rowbase = blockIdx.x * 64;

#pragma unroll
    for (int ch = 0; ch < 4; ++ch) {
        int flat = ch * 256 + t;
        int r = flat >> 4, g = flat & 15;
        int gr = rowbase + r;
        short8 frag = {0, 0, 0, 0, 0, 0, 0, 0};
        if (gr < nrows) {
            const float4* src = (const float4*)Asrc;
            float4 a0 = src[(size_t)gr * 32 + g * 2];
            float4 a1 = src[(size_t)gr * 32 + g * 2 + 1];
            frag[0] = (short)cvbf(a0.x);
            frag[1] = (short)cvbf(a0.y);
            frag[2] = (short)cvbf(a0.z);
            frag[3] = (short)cvbf(a0.w);
            frag[4] = (short)cvbf(a1.x);
            frag[5] = (short)cvbf(a1.y);
            frag[6] = (short)cvbf(a1.z);
            frag[7] = (short)cvbf(a1.w);
        }
        As[r * 16 + (g ^ (r & 7))] = frag;
    }

    int lane = t & 63;
    int w = t >> 6;
    int c0 = w * 32;
    int lrow = lane & 15;
    int lk = lane >> 4;
    int swz = lrow & 7;

    const short8* W1v = (const short8*)W1b;
    short8 bw[2][4];
#pragma unroll
    for (int ct = 0; ct < 2; ++ct)
#pragma unroll
        for (int ks = 0; ks < 4; ++ks)
            bw[ct][ks] = W1v[(size_t)(c0 + ct * 16 + lrow) * 16 + ks * 4 + lk];

    __syncthreads();

    f32x4 zero4 = {0.f, 0.f, 0.f, 0.f};
    f32x4 acc[4][2];
#pragma unroll
    for (int rt = 0; rt < 4; ++rt) {
        acc[rt][0] = zero4;
        acc[rt][1] = zero4;
    }
#pragma unroll
    for (int ks = 0; ks < 4; ++ks) {
        short8 a[4];
#pragma unroll
        for (int rt = 0; rt < 4; ++rt)
            a[rt] = As[(rt * 16 + lrow) * 16 + ((ks * 4 + lk) ^ swz)];
#pragma unroll
        for (int rt = 0; rt < 4; ++rt) {
            acc[rt][0] = __builtin_amdgcn_mfma_f32_16x16x32_bf16(a[rt], bw[0][ks], acc[rt][0], 0, 0, 0);
            acc[rt][1] = __builtin_amdgcn_mfma_f32_16x16x32_bf16(a[rt], bw[1][ks], acc[rt][1], 0, 0, 0);
        }
    }

    float b1v[2] = {b1[c0 + lrow], b1[c0 + 16 + lrow]};
    __syncthreads();
#pragma unroll
    for (int rt = 0; rt < 4; ++rt) {
#pragma unroll
        for (int ct = 0; ct < 2; ++ct) {
            int c = c0 + ct * 16 + lrow;
#pragma unroll
            for (int reg = 0; reg < 4; ++reg) {
                int row = rt * 16 + lk * 4 + reg;
                Of[row * 128 + ((c + ((row >> 2) & 3) * 8) & 127)] = acc[rt][ct][reg] + b1v[ct];
            }
        }
    }
    __syncthreads();

    // readout: 8 fp32 per lane -> packed bf16 uint4 store (16B/lane)
#pragma unroll
    for (int ch = 0; ch < 4; ++ch) {
        int flat = ch * 256 + t;  // 0..1023 : 64 rows x 16 col-granules(8)
        int row = flat >> 4;
        int cg = flat & 15;
        int grow = rowbase + row;
        if (grow >= nrows) continue;
        int fo = row * 128 + ((cg * 8 + ((row >> 2) & 3) * 8) & 127);
        float4 v0 = *(const float4*)&Of[fo];
        float4 v1 = *(const float4*)&Of[fo + 4];
        uint4 ob;
        ob.x = ((unsigned)cvbf(v0.y) << 16) | (unsigned)cvbf(v0.x);
        ob.y = ((unsigned)cvbf(v0.w) << 16) | (unsigned)cvbf(v0.z);
        ob.z = ((unsigned)cvbf(v1.y) << 16) | (unsigned)cvbf(v1.x);
        ob.w = ((unsigned)cvbf(v1.w) << 16) | (unsigned)cvbf(v1.z);
        ((uint4*)outb)[(size_t)grow * 16 + cg] = ob;
    }
}

// ---------------- fused GNN layer: 16KB aliased LDS, bf16-carried h ----------------
// As (gathered bf16 agg, swizzled) -> GEMM1 -> Ts (bf16 T) -> GEMM2 -> Os (bf16 s) ->
// epilogue o = h_own + relu(s) with 16B/lane accesses throughout.
// Mid layers: write bf16 carry to hb_out (ping-pong, != hb_in). Last: fp32 to outf.
__global__ __launch_bounds__(256, 4) void gnnlayer_k(
    const unsigned* __restrict__ hb_in, const int* __restrict__ rp, const int* __restrict__ col,
    const int* __restrict__ cnt, const short* __restrict__ W1b, const float* __restrict__ b1,
    const short* __restrict__ W2b, const float* __restrict__ b2,
    float* __restrict__ outf, unsigned* __restrict__ hb_out, int nrows) {
    __shared__ __align__(16) char smem[16384];
    __shared__ float dflag[64];
    short8* As = (short8*)smem;
    short* TsS = (short*)smem;
    unsigned short* Os = (unsigned short*)smem;
    int t = threadIdx.x;
    int rowbase = blockIdx.x * 64;
    int lane = t & 63;
    int wv = __builtin_amdgcn_readfirstlane(t >> 6);  // 0..3

    // ---- gather-aggregate phase: this wave owns nodes nbase..nbase+16 ----
    {
        int nbase = rowbase + wv * 16;
        int rb[17];
#pragma unroll
        for (int i = 0; i <= 16; ++i)
            rb[i] = __builtin_amdgcn_readfirstlane(rp[min(nbase + i, N_NODES)]);
        int d[16];
        int maxd = 0;
#pragma unroll
        for (int i = 0; i < 16; ++i) {
            d[i] = rb[i + 1] - rb[i];
            maxd = max(maxd, d[i]);
        }

        float ax[16], ay[16];
        int u[16];
#pragma unroll
        for (int i = 0; i < 16; ++i) {
            ax[i] = 0.f;
            ay[i] = 0.f;
            u[i] = 0;
        }
#pragma unroll
        for (int i = 0; i < 16; ++i)
            if (0 < d[i]) u[i] = col[rb[i]];  // wave-uniform -> s_load

        for (int j = 0; j < maxd; ++j) {
            unsigned p[16];
#pragma unroll
            for (int i = 0; i < 16; ++i)
                p[i] = (j < d[i]) ? hb_in[(size_t)u[i] * 64 + lane] : 0u;
            int jn = j + 1;
#pragma unroll
            for (int i = 0; i < 16; ++i)
                if (jn < d[i]) u[i] = col[rb[i] + jn];
#pragma unroll
            for (int i = 0; i < 16; ++i) {
                ax[i] += bflo(p[i]);
                ay[i] += bfhi(p[i]);
            }
        }

        unsigned* AsU = (unsigned*)As;
        int g = lane >> 2;
        int dw = lane & 3;
#pragma unroll
        for (int i = 0; i < 16; ++i) {
            float inv = 1.0f / fmaxf((float)d[i], 1.0f);
            unsigned pv = ((unsigned)cvbf(ay[i] * inv) << 16) | (unsigned)cvbf(ax[i] * inv);
            int r = wv * 16 + i;
            AsU[(r * 16 + (g ^ (r & 7))) * 4 + dw] = pv;
        }
    }
    if (t < 64) {
        int gr = rowbase + t;
        dflag[t] = (gr < nrows && cnt[gr] > 0) ? 1.0f : 0.0f;
    }

    int c0 = wv * 32;
    int lrow = lane & 15;
    int lk = lane >> 4;
    int swz = lrow & 7;

    const short8* W1v = (const short8*)W1b;
    short8 bw[2][4];
#pragma unroll
    for (int ct = 0; ct < 2; ++ct)
#pragma unroll
        for (int ks = 0; ks < 4; ++ks)
            bw[ct][ks] = W1v[(size_t)(c0 + ct * 16 + lrow) * 16 + ks * 4 + lk];

    __syncthreads();  // As + dflag complete

    f32x4 zero4 = {0.f, 0.f, 0.f, 0.f};
    f32x4 acc[4][2];
#pragma unroll
    for (int rt = 0; rt < 4; ++rt) {
        acc[rt][0] = zero4;
        acc[rt][1] = zero4;
    }
#pragma unroll
    for (int ks = 0; ks < 4; ++ks) {
        short8 a[4];
#pragma unroll
        for (int rt = 0; rt < 4; ++rt)
            a[rt] = As[(rt * 16 + lrow) * 16 + ((ks * 4 + lk) ^ swz)];
#pragma unroll
        for (int rt = 0; rt < 4; ++rt) {
            acc[rt][0] = __builtin_amdgcn_mfma_f32_16x16x32_bf16(a[rt], bw[0][ks], acc[rt][0], 0, 0, 0);
            acc[rt][1] = __builtin_amdgcn_mfma_f32_16x16x32_bf16(a[rt], bw[1][ks], acc[rt][1], 0, 0, 0);
        }
    }

    const short8* W2v = (const short8*)W2b;
    short8 bw2[2][4];
#pragma unroll
    for (int ct = 0; ct < 2; ++ct)
#pragma unroll
        for (int ks = 0; ks < 4; ++ks)
            bw2[ct][ks] = W2v[(size_t)(c0 + ct * 16 + lrow) * 16 + ks * 4 + lk];

    float b1v[2] = {b1[c0 + lrow], b1[c0 + 16 + lrow]};
    __syncthreads();  // all As reads done; region becomes T tile
#pragma unroll
    for (int rt = 0; rt < 4; ++rt) {
#pragma unroll
        for (int ct = 0; ct < 2; ++ct) {
            int c = c0 + ct * 16 + lrow;
            int gh = c >> 3;
#pragma unroll
            for (int reg = 0; reg < 4; ++reg) {
                int rl = rt * 16 + lk * 4 + reg;  // C/D: row=(lane>>4)*4+reg
                float tv = acc[rt][ct][reg] + b1v[ct] * dflag[rl];
                TsS[rl * 128 + ((gh ^ (rl & 7)) << 3) + (c & 7)] = (short)cvbf(tv);
            }
        }
    }
    __syncthreads();  // T complete

    f32x4 acc2[4][2];
#pragma unroll
    for (int rt = 0; rt < 4; ++rt) {
        acc2[rt][0] = zero4;
        acc2[rt][1] = zero4;
    }
#pragma unroll
    for (int ks = 0; ks < 4; ++ks) {
        short8 a[4];
#pragma unroll
        for (int rt = 0; rt < 4; ++rt)
            a[rt] = As[(rt * 16 + lrow) * 16 + ((ks * 4 + lk) ^ swz)];  // region holds T now
#pragma unroll
        for (int rt = 0; rt < 4; ++rt) {
            acc2[rt][0] = __builtin_amdgcn_mfma_f32_16x16x32_bf16(a[rt], bw2[0][ks], acc2[rt][0], 0, 0, 0);
            acc2[rt][1] = __builtin_amdgcn_mfma_f32_16x16x32_bf16(a[rt], bw2[1][ks], acc2[rt][1], 0, 0, 0);
        }
    }

    float b2v[2] = {b2[c0 + lrow], b2[c0 + 16 + lrow]};
    __syncthreads();  // all T reads done; region becomes s tile (bf16)
#pragma unroll
    for (int rt = 0; rt < 4; ++rt) {
#pragma unroll
        for (int ct = 0; ct < 2; ++ct) {
            int c = c0 + ct * 16 + lrow;
            int gh = c >> 3;
#pragma unroll
            for (int reg = 0; reg < 4; ++reg) {
                int rl = rt * 16 + lk * 4 + reg;
                Os[rl * 128 + ((gh ^ (rl & 7)) << 3) + (c & 7)] =
                    cvbf(acc2[rt][ct][reg] + b2v[ct]);
            }
        }
    }
    __syncthreads();

    // epilogue: o = h_own + relu(s). 16B/lane: uint4 own-row read, uint4 LDS read,
    // uint4 bf16 mirror write and/or 2x float4 fp32 write (last layer).
    const uint4* Hb16 = (const uint4*)hb_in;
#pragma unroll
    for (int ch = 0; ch < 4; ++ch) {
        int flat = ch * 256 + t;  // 0..1023 : 64 rows x 16 col-granules(8)
        int row = flat >> 4;
        int cg = flat & 15;
        int grow = rowbase + row;
        if (grow >= nrows) continue;
        uint4 sv = *(const uint4*)&Os[row * 128 + ((cg ^ (row & 7)) << 3)];
        uint4 hv = Hb16[(size_t)grow * 16 + cg];
        float o[8];
        const unsigned* sp = (const unsigned*)&sv;
        const unsigned* hp = (const unsigned*)&hv;
#pragma unroll
        for (int j = 0; j < 4; ++j) {
            o[2 * j + 0] = bflo(hp[j]) + fmaxf(bflo(sp[j]), 0.f);
            o[2 * j + 1] = bfhi(hp[j]) + fmaxf(bfhi(sp[j]), 0.f);
        }
        if (hb_out) {
            uint4 ob;
            ob.x = ((unsigned)cvbf(o[1]) << 16) | (unsigned)cvbf(o[0]);
            ob.y = ((unsigned)cvbf(o[3]) << 16) | (unsigned)cvbf(o[2]);
            ob.z = ((unsigned)cvbf(o[5]) << 16) | (unsigned)cvbf(o[4]);
            ob.w = ((unsigned)cvbf(o[7]) << 16) | (unsigned)cvbf(o[6]);
            ((uint4*)hb_out)[(size_t)grow * 16 + cg] = ob;
        }
        if (outf) {
            float4 f0 = make_float4(o[0], o[1], o[2], o[3]);
            float4 f1 = make_float4(o[4], o[5], o[6], o[7]);
            ((float4*)outf)[(size_t)grow * 32 + cg * 2 + 0] = f0;
            ((float4*)outf)[(size_t)grow * 32 + cg * 2 + 1] = f1;
        }
    }
}

extern "C" void kernel_launch(void* const* d_in, const int* in_sizes, int n_in,
                              void* d_out, int out_size, void* d_ws, size_t ws_size,
                              hipStream_t stream) {
    const float* x = (const float*)d_in[0];
    const float* Wi = (const float*)d_in[1];
    const float* bi = (const float*)d_in[2];
    const float* Wm = (const float*)d_in[3];
    const float* bm = (const float*)d_in[4];
    const float* Wu = (const float*)d_in[5];
    const float* bu = (const float*)d_in[6];
    const int* edge = (const int*)d_in[7];
    float* h = (float*)d_out;

    char* ws = (char*)d_ws;
    size_t off = 0;
    auto alloc = [&](size_t bytes) {
        void* p = ws + off;
        off += (bytes + 255) & ~(size_t)255;
        return p;
    };
    // ping-pong bf16 h buffers (the carried representation between layers)
    unsigned* hbuf[2];
    hbuf[0] = (unsigned*)alloc((size_t)N_NODES * D * 2);
    hbuf[1] = (unsigned*)alloc((size_t)N_NODES * D * 2);
    unsigned short* Wi_bf = (unsigned short*)alloc((size_t)D * D * 2);
    unsigned short* Wm_bf = (unsigned short*)alloc((size_t)NLAYERS * D * D * 2);
    unsigned short* Wu_bf = (unsigned short*)alloc((size_t)NLAYERS * D * D * 2);
    int* cnt = (int*)alloc((size_t)N_NODES * sizeof(int));
    int* rp = (int*)alloc((size_t)(N_NODES + 1) * sizeof(int));
    int* fill = (int*)alloc((size_t)N_NODES * sizeof(int));
    int* bsum = (int*)alloc(1024 * sizeof(int));
    int* col = (int*)alloc((size_t)N_EDGES * sizeof(int));

    const int scan_blocks = (N_NODES + 1023) / 1024;  // 98
    const int edge_blocks = (N_EDGES + 255) / 256;    // 2500
    const int gemm_blocks = (N_NODES + 63) / 64;      // 1563

    // CSR build
    hipMemsetAsync(cnt, 0, (size_t)N_NODES * sizeof(int), stream);
    count_kernel<<<edge_blocks, 256, 0, stream>>>(edge, cnt);
    scan_local<<<scan_blocks, 256, 0, stream>>>(cnt, rp, bsum);
    scan_add<<<scan_blocks, 256, 0, stream>>>(rp, fill, bsum);
    fill_kernel<<<edge_blocks, 256, 0, stream>>>(edge, fill, col);

    // weights -> bf16
    wconv<<<(D * D / 4 + 255) / 256, 256, 0, stream>>>(Wi, Wi_bf, D * D / 4);
    wconv<<<(NLAYERS * D * D / 4 + 255) / 256, 256, 0, stream>>>(Wm, Wm_bf, NLAYERS * D * D / 4);
    wconv<<<(NLAYERS * D * D / 4 + 255) / 256, 256, 0, stream>>>(Wu, Wu_bf, NLAYERS * D * D / 4);

    // input projection: hbuf[0] = bf16(x @ Wi^T + bi)
    proj_k<<<gemm_blocks, 256, 0, stream>>>(x, (const short*)Wi_bf, bi, hbuf[0], N_NODES);

    for (int l = 0; l < NLAYERS; ++l) {
        // layer l: read hbuf[l&1]; mid -> bf16 carry into hbuf[(l+1)&1]; last -> fp32 d_out
        unsigned* hb_out = (l == NLAYERS - 1) ? nullptr : hbuf[(l + 1) & 1];
        float* outf = (l == NLAYERS - 1) ? h : nullptr;
        gnnlayer_k<<<gemm_blocks, 256, 0, stream>>>(
            hbuf[l & 1], rp, col, cnt,
            (const short*)(Wm_bf + (size_t)l * D * D), bm + (size_t)l * D,
            (const short*)(Wu_bf + (size_t)l * D * D), bu + (size_t)l * D, outf, hb_out,
            N_NODES);
    }
}